// Round 2
// baseline (20484.314 us; speedup 1.0000x reference)
//
#include <hip/hip_runtime.h>
#include <hip/hip_cooperative_groups.h>
#include <math.h>

namespace cg = cooperative_groups;

#define Bn   32
#define Tn   256
#define DIN  768
#define DHn  512
#define DEn  25
#define Cn   9
#define K3   2304   // 3*DIN
#define H3   1536   // 3*DH
#define NCOL 3072   // 2*H3
#define MROW 8192   // B*T

// ---------------- gi pre-GEMM: gi[m][n] = lmr[m][:] . W[n][:] + bih[n] ----------------
#define BM 128
#define BN 128
#define BK 16

__global__ __launch_bounds__(256) void gi_gemm_kernel(
    const float* __restrict__ X, const float* __restrict__ pad,
    const float* __restrict__ Wf, const float* __restrict__ Wb,
    const float* __restrict__ bf, const float* __restrict__ bb,
    float* __restrict__ gi)
{
  __shared__ __align__(16) float As[BK][BM + 4];
  __shared__ __align__(16) float Bs[BK][BN + 4];
  const int bm = blockIdx.x, bn = blockIdx.y;
  const int tid = threadIdx.x;
  const int tx = tid & 15, ty = tid >> 4;
  const int m0 = bm * BM, n0 = bn * BN;
  const bool isF = (n0 < H3);
  const float* Wmat = isF ? Wf : Wb;
  const float* bias = isF ? bf : bb;
  const int nbase = isF ? n0 : (n0 - H3);

  float acc[8][8];
#pragma unroll
  for (int i = 0; i < 8; i++)
#pragma unroll
    for (int j = 0; j < 8; j++) acc[i][j] = 0.f;

  const int lrow = tid >> 2;       // 0..63
  const int lk = (tid & 3) * 4;    // 0,4,8,12

  for (int k0 = 0; k0 < K3; k0 += BK) {
#pragma unroll
    for (int i = 0; i < 2; i++) {
      int row = lrow + i * 64;
      int m = m0 + row;
      int b = m >> 8, t = m & 255;
      int kg = k0 + lk;
      int seg = (kg >= DIN) + (kg >= 2 * DIN);
      int off = kg - seg * DIN;
      int p = t + seg;                       // position in X_pad: 0..257
      float4 v;
      if (p == 0 || p == Tn + 1) v = *reinterpret_cast<const float4*>(pad + off);
      else v = *reinterpret_cast<const float4*>(X + (size_t)(b * Tn + (p - 1)) * DIN + off);
      As[lk + 0][row] = v.x; As[lk + 1][row] = v.y;
      As[lk + 2][row] = v.z; As[lk + 3][row] = v.w;
    }
#pragma unroll
    for (int i = 0; i < 2; i++) {
      int row = lrow + i * 64;
      const float* wp = Wmat + (size_t)(nbase + row) * K3 + k0 + lk;
      float4 v = *reinterpret_cast<const float4*>(wp);
      Bs[lk + 0][row] = v.x; Bs[lk + 1][row] = v.y;
      Bs[lk + 2][row] = v.z; Bs[lk + 3][row] = v.w;
    }
    __syncthreads();
#pragma unroll
    for (int kk = 0; kk < BK; kk++) {
      float4 a0 = *reinterpret_cast<const float4*>(&As[kk][ty * 8]);
      float4 a1 = *reinterpret_cast<const float4*>(&As[kk][ty * 8 + 4]);
      float4 b0 = *reinterpret_cast<const float4*>(&Bs[kk][tx * 8]);
      float4 b1 = *reinterpret_cast<const float4*>(&Bs[kk][tx * 8 + 4]);
      float av[8] = {a0.x, a0.y, a0.z, a0.w, a1.x, a1.y, a1.z, a1.w};
      float bv[8] = {b0.x, b0.y, b0.z, b0.w, b1.x, b1.y, b1.z, b1.w};
#pragma unroll
      for (int i = 0; i < 8; i++)
#pragma unroll
        for (int j = 0; j < 8; j++)
          acc[i][j] = fmaf(av[i], bv[j], acc[i][j]);
    }
    __syncthreads();
  }
#pragma unroll
  for (int i = 0; i < 8; i++) {
    int m = m0 + ty * 8 + i;
    float* orow = gi + (size_t)m * NCOL + n0 + tx * 8;
    float4 o0, o1;
    o0.x = acc[i][0] + bias[nbase + tx * 8 + 0];
    o0.y = acc[i][1] + bias[nbase + tx * 8 + 1];
    o0.z = acc[i][2] + bias[nbase + tx * 8 + 2];
    o0.w = acc[i][3] + bias[nbase + tx * 8 + 3];
    o1.x = acc[i][4] + bias[nbase + tx * 8 + 4];
    o1.y = acc[i][5] + bias[nbase + tx * 8 + 5];
    o1.z = acc[i][6] + bias[nbase + tx * 8 + 6];
    o1.w = acc[i][7] + bias[nbase + tx * 8 + 7];
    *reinterpret_cast<float4*>(orow) = o0;
    *reinterpret_cast<float4*>(orow + 4) = o1;
  }
}

// ---------------- Whh prep: [dir][g(128)][u_loc(4)][gate(3)][k(512)] ----------------
__global__ __launch_bounds__(256) void whh_prep_kernel(
    const float* __restrict__ Wf, const float* __restrict__ Wb, float* __restrict__ WtG)
{
  int f = blockIdx.x * 256 + threadIdx.x;
  if (f >= 2 * H3 * DHn) return;
  int k = f & 511;
  int r3 = f >> 9;          // 0..3071
  int gate = r3 % 3;
  int r4 = r3 / 3;          // 0..1023
  int u_loc = r4 & 3;
  int r5 = r4 >> 2;         // 0..255
  int g = r5 & 127;
  int dir = r5 >> 7;
  int u_glob = g * 4 + u_loc;
  const float* W = dir ? Wb : Wf;
  WtG[f] = W[(size_t)(gate * DHn + u_glob) * DHn + k];
}

// ---------------- GRU recurrence: 256 WGs, each owns 4 units x all 32 batches ----------------
// hbuf layout: [dir][par][b(32)][u(512)] floats
__global__ __launch_bounds__(256) void gru_rec2_kernel(
    const float* __restrict__ gi,     // [8192][3072]
    const float* __restrict__ WtG,    // [2][128][4][3][512]
    const float* __restrict__ bhh_f, const float* __restrict__ bhh_b,
    float* __restrict__ hbuf,         // [2][2][32][512]
    float* __restrict__ out)          // [B][T][1024]
{
  cg::grid_group grid = cg::this_grid();
  __shared__ __align__(16) float4 w_lds[4][3][128];   // [u_loc][gate][k4]
  __shared__ __align__(16) float h_lds[32][516];      // stride 516 ≡ 4 (mod 32), 16B aligned

  const int wg = blockIdx.x;
  const int dir = wg >> 7, g = wg & 127;
  const int tid = threadIdx.x;
  const int wv = tid >> 6;           // wave id = local unit
  const int l = tid & 63;
  const int b = l & 31, kh = l >> 5; // batch, k-half
  const int u_glob = g * 4 + wv;

  // stage this WG's weight slice into LDS (once)
  {
    const float4* wsrc = reinterpret_cast<const float4*>(WtG + (size_t)wg * 6144);
    float4* wl = &w_lds[0][0][0];
    for (int i = tid; i < 1536; i += 256) wl[i] = wsrc[i];
  }
  // zero h state
  for (int i = tid; i < 32 * 516; i += 256) (&h_lds[0][0])[i] = 0.f;

  const float* bhh = dir ? bhh_b : bhh_f;
  const float br = bhh[u_glob], bz = bhh[DHn + u_glob], bn = bhh[2 * DHn + u_glob];
  float* hb_dir = hbuf + (size_t)dir * 2 * Bn * DHn;

  __syncthreads();

  for (int s = 0; s < Tn; s++) {
    if (s > 0) {
      // stage h(s-1) from global exchange buffer into LDS (with [b][u] layout)
      const int par = (s - 1) & 1;
      const float4* src = reinterpret_cast<const float4*>(hb_dir + (size_t)par * Bn * DHn);
#pragma unroll
      for (int it = 0; it < 16; it++) {
        int i = tid + it * 256;           // float4 index, 0..4095
        float4 v = src[i];
        int f0 = i * 4;
        int bb = f0 >> 9, uu = f0 & 511;
        *reinterpret_cast<float4*>(&h_lds[bb][uu]) = v;
      }
      __syncthreads();
    }

    const int t = dir ? (Tn - 1 - s) : s;
    // gi values (global, issue early)
    const float* gp = gi + (size_t)(b * Tn + t) * NCOL + dir * H3 + u_glob;
    const float ir = gp[0], iz = gp[DHn], inn = gp[2 * DHn];
    const float hold = h_lds[b][u_glob];

    // dot over this thread's k-half
    float4 ar = {0.f, 0.f, 0.f, 0.f}, az = ar, an = ar;
    const float4* hp = reinterpret_cast<const float4*>(&h_lds[b][kh * 256]);
    const float4* wr = &w_lds[wv][0][kh * 64];
    const float4* wz = &w_lds[wv][1][kh * 64];
    const float4* wn = &w_lds[wv][2][kh * 64];
#pragma unroll 8
    for (int i = 0; i < 64; i++) {
      float4 hv = hp[i];
      float4 w1 = wr[i], w2 = wz[i], w3 = wn[i];
      ar.x = fmaf(hv.x, w1.x, ar.x); ar.y = fmaf(hv.y, w1.y, ar.y);
      ar.z = fmaf(hv.z, w1.z, ar.z); ar.w = fmaf(hv.w, w1.w, ar.w);
      az.x = fmaf(hv.x, w2.x, az.x); az.y = fmaf(hv.y, w2.y, az.y);
      az.z = fmaf(hv.z, w2.z, az.z); az.w = fmaf(hv.w, w2.w, az.w);
      an.x = fmaf(hv.x, w3.x, an.x); an.y = fmaf(hv.y, w3.y, an.y);
      an.z = fmaf(hv.z, w3.z, an.z); an.w = fmaf(hv.w, w3.w, an.w);
    }
    float sr = (ar.x + ar.y) + (ar.z + ar.w);
    float sz = (az.x + az.y) + (az.z + az.w);
    float sn = (an.x + an.y) + (an.z + an.w);
    sr += __shfl_xor(sr, 32);
    sz += __shfl_xor(sz, 32);
    sn += __shfl_xor(sn, 32);

    const float r = 1.f / (1.f + expf(-(ir + sr + br)));
    const float z = 1.f / (1.f + expf(-(iz + sz + bz)));
    const float n = tanhf(inn + r * (sn + bn));
    const float hnew = (1.f - z) * n + z * hold;

    if (kh == 0) {
      hb_dir[(size_t)(s & 1) * Bn * DHn + b * DHn + u_glob] = hnew;
    } else {
      out[(size_t)(b * Tn + t) * 1024 + dir * DHn + u_glob] = hnew;
    }
    if (s < Tn - 1) {
      __threadfence();
      grid.sync();
    }
  }
}

// ---------------- decoder: per-batch sequential argmax-feedback chain ----------------
__global__ __launch_bounds__(64) void decoder_kernel(
    const float* __restrict__ out_h,      // [B][T][1024] (already in d_out)
    const float* __restrict__ label_emb,  // [10][25]
    const float* __restrict__ Wc,         // [9][1049]
    const float* __restrict__ bc,         // [9]
    float* __restrict__ out_chunk)        // [B*T][9]
{
  __shared__ float wcs[Cn * 1049];
  __shared__ float embs[(Cn + 1) * DEn];
  const int b = blockIdx.x;
  const int lane = threadIdx.x;
  for (int i = lane; i < Cn * 1049; i += 64) wcs[i] = Wc[i];
  for (int i = lane; i < (Cn + 1) * DEn; i += 64) embs[i] = label_emb[i];
  float bcv[Cn];
#pragma unroll
  for (int c = 0; c < Cn; c++) bcv[c] = bc[c];
  __syncthreads();

  int prev = Cn;  // start token
  for (int t = 0; t < Tn; t++) {
    const float* ht = out_h + (size_t)(b * Tn + t) * 1024;
    float hreg[16];
#pragma unroll
    for (int i = 0; i < 16; i++) hreg[i] = ht[lane + 64 * i];
    float acc[Cn];
#pragma unroll
    for (int c = 0; c < Cn; c++) {
      const float* wrow = &wcs[c * 1049];
      float a = 0.f;
#pragma unroll
      for (int i = 0; i < 16; i++) a = fmaf(hreg[i], wrow[lane + 64 * i], a);
      if (lane < DEn) a = fmaf(embs[prev * DEn + lane], wrow[1024 + lane], a);
      acc[c] = a;
    }
#pragma unroll
    for (int off = 32; off; off >>= 1)
#pragma unroll
      for (int c = 0; c < Cn; c++) acc[c] += __shfl_xor(acc[c], off);
#pragma unroll
    for (int c = 0; c < Cn; c++) acc[c] += bcv[c];
    float mx = acc[0]; int idx = 0;
#pragma unroll
    for (int c = 1; c < Cn; c++) if (acc[c] > mx) { mx = acc[c]; idx = c; }
    float e[Cn]; float sum = 0.f;
#pragma unroll
    for (int c = 0; c < Cn; c++) { e[c] = expf(acc[c] - mx); sum += e[c]; }
    float inv = 1.f / sum;
    if (lane < Cn) out_chunk[(size_t)(b * Tn + t) * Cn + lane] = e[lane] * inv;
    prev = idx;
  }
}

extern "C" void kernel_launch(void* const* d_in, const int* in_sizes, int n_in,
                              void* d_out, int out_size, void* d_ws, size_t ws_size,
                              hipStream_t stream) {
  const float* X      = (const float*)d_in[0];
  const float* pad    = (const float*)d_in[1];
  const float* lemb   = (const float*)d_in[2];
  const float* Wih_f  = (const float*)d_in[3];
  const float* Whh_f  = (const float*)d_in[4];
  const float* bih_f  = (const float*)d_in[5];
  const float* bhh_f  = (const float*)d_in[6];
  const float* Wih_b  = (const float*)d_in[7];
  const float* Whh_b  = (const float*)d_in[8];
  const float* bih_b  = (const float*)d_in[9];
  const float* bhh_b  = (const float*)d_in[10];
  const float* Wc     = (const float*)d_in[11];
  const float* bc     = (const float*)d_in[12];
  float* out = (float*)d_out;

  float* gi   = (float*)d_ws;                                        // 100,663,296 B
  float* WtG  = (float*)((char*)d_ws + (size_t)MROW * NCOL * 4);     // + 6,291,456 B
  float* hbuf = (float*)((char*)d_ws + (size_t)MROW * NCOL * 4 + (size_t)2 * H3 * DHn * 4); // + 262,144 B

  whh_prep_kernel<<<dim3((2 * H3 * DHn + 255) / 256), dim3(256), 0, stream>>>(Whh_f, Whh_b, WtG);
  gi_gemm_kernel<<<dim3(MROW / BM, NCOL / BN), dim3(256), 0, stream>>>(X, pad, Wih_f, Wih_b, bih_f, bih_b, gi);

  {
    void* args[] = {(void*)&gi, (void*)&WtG, (void*)&bhh_f, (void*)&bhh_b, (void*)&hbuf, (void*)&out};
    hipLaunchCooperativeKernel((const void*)gru_rec2_kernel, dim3(256), dim3(256), args, 0, stream);
  }

  decoder_kernel<<<dim3(Bn), dim3(64), 0, stream>>>(out, lemb, Wc, bc, out + (size_t)MROW * 1024);
}

// Round 3
// 4906.407 us; speedup vs baseline: 4.1750x; 4.1750x over previous
//
#include <hip/hip_runtime.h>
#include <hip/hip_cooperative_groups.h>
#include <math.h>

#define Bn   32
#define Tn   256
#define DIN  768
#define DHn  512
#define DEn  25
#define Cn   9
#define K3   2304   // 3*DIN
#define H3   1536   // 3*DH
#define NCOL 3072   // 2*H3
#define MROW 8192   // B*T

// ---------------- gi pre-GEMM: gi[m][n] = lmr[m][:] . W[n][:] + bih[n] ----------------
#define BM 128
#define BN 128
#define BK 16

__global__ __launch_bounds__(256) void gi_gemm_kernel(
    const float* __restrict__ X, const float* __restrict__ pad,
    const float* __restrict__ Wf, const float* __restrict__ Wb,
    const float* __restrict__ bf, const float* __restrict__ bb,
    float* __restrict__ gi)
{
  __shared__ __align__(16) float As[BK][BM + 4];
  __shared__ __align__(16) float Bs[BK][BN + 4];
  const int bm = blockIdx.x, bn = blockIdx.y;
  const int tid = threadIdx.x;
  const int tx = tid & 15, ty = tid >> 4;
  const int m0 = bm * BM, n0 = bn * BN;
  const bool isF = (n0 < H3);
  const float* Wmat = isF ? Wf : Wb;
  const float* bias = isF ? bf : bb;
  const int nbase = isF ? n0 : (n0 - H3);

  float acc[8][8];
#pragma unroll
  for (int i = 0; i < 8; i++)
#pragma unroll
    for (int j = 0; j < 8; j++) acc[i][j] = 0.f;

  const int lrow = tid >> 2;       // 0..63
  const int lk = (tid & 3) * 4;    // 0,4,8,12

  for (int k0 = 0; k0 < K3; k0 += BK) {
#pragma unroll
    for (int i = 0; i < 2; i++) {
      int row = lrow + i * 64;
      int m = m0 + row;
      int b = m >> 8, t = m & 255;
      int kg = k0 + lk;
      int seg = (kg >= DIN) + (kg >= 2 * DIN);
      int off = kg - seg * DIN;
      int p = t + seg;                       // position in X_pad: 0..257
      float4 v;
      if (p == 0 || p == Tn + 1) v = *reinterpret_cast<const float4*>(pad + off);
      else v = *reinterpret_cast<const float4*>(X + (size_t)(b * Tn + (p - 1)) * DIN + off);
      As[lk + 0][row] = v.x; As[lk + 1][row] = v.y;
      As[lk + 2][row] = v.z; As[lk + 3][row] = v.w;
    }
#pragma unroll
    for (int i = 0; i < 2; i++) {
      int row = lrow + i * 64;
      const float* wp = Wmat + (size_t)(nbase + row) * K3 + k0 + lk;
      float4 v = *reinterpret_cast<const float4*>(wp);
      Bs[lk + 0][row] = v.x; Bs[lk + 1][row] = v.y;
      Bs[lk + 2][row] = v.z; Bs[lk + 3][row] = v.w;
    }
    __syncthreads();
#pragma unroll
    for (int kk = 0; kk < BK; kk++) {
      float4 a0 = *reinterpret_cast<const float4*>(&As[kk][ty * 8]);
      float4 a1 = *reinterpret_cast<const float4*>(&As[kk][ty * 8 + 4]);
      float4 b0 = *reinterpret_cast<const float4*>(&Bs[kk][tx * 8]);
      float4 b1 = *reinterpret_cast<const float4*>(&Bs[kk][tx * 8 + 4]);
      float av[8] = {a0.x, a0.y, a0.z, a0.w, a1.x, a1.y, a1.z, a1.w};
      float bv[8] = {b0.x, b0.y, b0.z, b0.w, b1.x, b1.y, b1.z, b1.w};
#pragma unroll
      for (int i = 0; i < 8; i++)
#pragma unroll
        for (int j = 0; j < 8; j++)
          acc[i][j] = fmaf(av[i], bv[j], acc[i][j]);
    }
    __syncthreads();
  }
#pragma unroll
  for (int i = 0; i < 8; i++) {
    int m = m0 + ty * 8 + i;
    float* orow = gi + (size_t)m * NCOL + n0 + tx * 8;
    float4 o0, o1;
    o0.x = acc[i][0] + bias[nbase + tx * 8 + 0];
    o0.y = acc[i][1] + bias[nbase + tx * 8 + 1];
    o0.z = acc[i][2] + bias[nbase + tx * 8 + 2];
    o0.w = acc[i][3] + bias[nbase + tx * 8 + 3];
    o1.x = acc[i][4] + bias[nbase + tx * 8 + 4];
    o1.y = acc[i][5] + bias[nbase + tx * 8 + 5];
    o1.z = acc[i][6] + bias[nbase + tx * 8 + 6];
    o1.w = acc[i][7] + bias[nbase + tx * 8 + 7];
    *reinterpret_cast<float4*>(orow) = o0;
    *reinterpret_cast<float4*>(orow + 4) = o1;
  }
}

// ---------------- prep: Wp[d][slice(32)][u(16)][k(512)*3+pad] + zero sync counters ----------------
#define WSTRIDE 1540   // dwords per unit row (512*3 + 4 pad; %32 == 4 for bank spread)
#define HSTRIDE 12     // dwords per k row of h_lds (8 batches + 4 pad)

__global__ __launch_bounds__(256) void prep_kernel(
    const float* __restrict__ Whh_f, const float* __restrict__ Whh_b,
    float* __restrict__ Wp, unsigned* __restrict__ sync)
{
  int f = blockIdx.x * 256 + threadIdx.x;
  if (f < 8) sync[f * 32] = 0u;
  const int total = 2 * 32 * 16 * 512 * 3;   // 1,572,864
  if (f >= total) return;
  int gate = f % 3;
  int k    = (f / 3) & 511;
  int u    = (f / 1536) & 15;
  int slc  = (f / 24576) & 31;
  int dd   = f / 786432;
  const float* Wsrc = dd ? Whh_b : Whh_f;
  float v = Wsrc[(size_t)(gate * DHn + slc * 16 + u) * DHn + k];
  Wp[((size_t)(dd * 32 + slc) * 16 + u) * WSTRIDE + k * 3 + gate] = v;
}

// ---------------- GRU recurrence: weights-stationary, per-group lean barriers ----------------
// WG(bid): xcd=bid&7 -> d=xcd>>2, g=xcd&3 (sync group, intra-XCD), slice=bid>>3.
// hex: [par(2)][grp(8)][b(8)][u(512)] floats. sync: 8 counters, stride 32 dwords.
__global__ __launch_bounds__(256) void gru_rec3_kernel(
    const float* __restrict__ gi,     // [8192][3072]
    const float* __restrict__ Wp,     // [2][32][16][WSTRIDE]
    const float* __restrict__ bhh_f, const float* __restrict__ bhh_b,
    unsigned* __restrict__ sync,
    float* __restrict__ hex,
    float* __restrict__ out)          // [B][T][1024]
{
  __shared__ __align__(16) float W[16 * WSTRIDE];     // 98,560 B
  __shared__ __align__(16) float hl[512 * HSTRIDE];   // 24,576 B

  const int bid = blockIdx.x;
  const int xcd = bid & 7;
  const int d = xcd >> 2, g = xcd & 3;
  const int sl = bid >> 3;                  // unit slice 0..31
  const int tid = threadIdx.x;
  const int ut = tid >> 4;                  // unit-local 0..15
  const int kq = tid & 15;                  // k-slice 0..15
  const int grp = d * 4 + g;

  // stage weights (once)
  {
    const float* src = Wp + (size_t)(d * 32 + sl) * 16 * WSTRIDE;
    for (int i = tid; i < 16 * WSTRIDE; i += 256) W[i] = src[i];
  }
  for (int i = tid; i < 512 * HSTRIDE; i += 256) hl[i] = 0.f;

  const float* bhh = d ? bhh_b : bhh_f;
  const int ug = sl * 16 + ut;              // global unit for epilogue
  const float br = bhh[ug], bz = bhh[DHn + ug], bn2 = bhh[2 * DHn + ug];
  // reduce-scatter final batch owned by this lane (kq<8 active)
  const int b_l = ((kq & 1) << 2) | (kq & 2) | ((kq >> 2) & 1);

  unsigned* cnt = sync + grp * 32;

  __syncthreads();

  for (int s = 0; s < Tn; s++) {
    if (s > 0) {
      if (tid == 0) {
        const unsigned tgt = 32u * (unsigned)s;
        while (__hip_atomic_load(cnt, __ATOMIC_RELAXED, __HIP_MEMORY_SCOPE_AGENT) < tgt)
          __builtin_amdgcn_s_sleep(2);
        (void)__hip_atomic_load(cnt, __ATOMIC_ACQUIRE, __HIP_MEMORY_SCOPE_AGENT);
      }
      __syncthreads();
      // readback h(s-1): coalesced global read, transpose into hl[k][b]
      const float* src = hex + (size_t)(((s - 1) & 1) * 8 + grp) * (8 * 512);
#pragma unroll
      for (int it = 0; it < 16; it++) {
        int idx = it * 256 + tid;
        float v = src[idx];
        hl[(idx & 511) * HSTRIDE + (idx >> 9)] = v;
      }
      __syncthreads();
    }

    const int t = d ? (Tn - 1 - s) : s;

    // gi prefetch for this lane's (ug, b_l)
    float ir = 0.f, iz = 0.f, inn = 0.f;
    if (kq < 8) {
      const int bg = g * 8 + b_l;
      const float* gp = gi + (size_t)(bg * Tn + t) * NCOL + d * H3 + ug;
      ir = gp[0]; iz = gp[DHn]; inn = gp[2 * DHn];
    }

    float acc[3][8];
#pragma unroll
    for (int gg = 0; gg < 3; gg++)
#pragma unroll
      for (int bb = 0; bb < 8; bb++) acc[gg][bb] = 0.f;

#pragma unroll 4
    for (int i = 0; i < 32; i++) {
      int k = i * 16 + kq;
      const float* wp = &W[ut * WSTRIDE + k * 3];
      float w0 = wp[0], w1 = wp[1], w2 = wp[2];
      const float* hp = &hl[k * HSTRIDE];
      float4 ha = *reinterpret_cast<const float4*>(hp);
      float4 hb = *reinterpret_cast<const float4*>(hp + 4);
      acc[0][0] = fmaf(w0, ha.x, acc[0][0]); acc[0][1] = fmaf(w0, ha.y, acc[0][1]);
      acc[0][2] = fmaf(w0, ha.z, acc[0][2]); acc[0][3] = fmaf(w0, ha.w, acc[0][3]);
      acc[0][4] = fmaf(w0, hb.x, acc[0][4]); acc[0][5] = fmaf(w0, hb.y, acc[0][5]);
      acc[0][6] = fmaf(w0, hb.z, acc[0][6]); acc[0][7] = fmaf(w0, hb.w, acc[0][7]);
      acc[1][0] = fmaf(w1, ha.x, acc[1][0]); acc[1][1] = fmaf(w1, ha.y, acc[1][1]);
      acc[1][2] = fmaf(w1, ha.z, acc[1][2]); acc[1][3] = fmaf(w1, ha.w, acc[1][3]);
      acc[1][4] = fmaf(w1, hb.x, acc[1][4]); acc[1][5] = fmaf(w1, hb.y, acc[1][5]);
      acc[1][6] = fmaf(w1, hb.z, acc[1][6]); acc[1][7] = fmaf(w1, hb.w, acc[1][7]);
      acc[2][0] = fmaf(w2, ha.x, acc[2][0]); acc[2][1] = fmaf(w2, ha.y, acc[2][1]);
      acc[2][2] = fmaf(w2, ha.z, acc[2][2]); acc[2][3] = fmaf(w2, ha.w, acc[2][3]);
      acc[2][4] = fmaf(w2, hb.x, acc[2][4]); acc[2][5] = fmaf(w2, hb.y, acc[2][5]);
      acc[2][6] = fmaf(w2, hb.z, acc[2][6]); acc[2][7] = fmaf(w2, hb.w, acc[2][7]);
    }

    // mask-8 full add: pair {kq, kq+8}
#pragma unroll
    for (int gg = 0; gg < 3; gg++)
#pragma unroll
      for (int bb = 0; bb < 8; bb++)
        acc[gg][bb] += __shfl_xor(acc[gg][bb], 8);

    // reduce-scatter masks 1,2,4 (halving arrays; all indices compile-time)
    float a4[3][4];
#pragma unroll
    for (int gg = 0; gg < 3; gg++)
#pragma unroll
      for (int j = 0; j < 4; j++) {
        float keep = (kq & 1) ? acc[gg][4 + j] : acc[gg][j];
        float send = (kq & 1) ? acc[gg][j] : acc[gg][4 + j];
        a4[gg][j] = keep + __shfl_xor(send, 1);
      }
    float a2[3][2];
#pragma unroll
    for (int gg = 0; gg < 3; gg++)
#pragma unroll
      for (int j = 0; j < 2; j++) {
        float keep = (kq & 2) ? a4[gg][2 + j] : a4[gg][j];
        float send = (kq & 2) ? a4[gg][j] : a4[gg][2 + j];
        a2[gg][j] = keep + __shfl_xor(send, 2);
      }
    float a1[3];
#pragma unroll
    for (int gg = 0; gg < 3; gg++) {
      float keep = (kq & 4) ? a2[gg][1] : a2[gg][0];
      float send = (kq & 4) ? a2[gg][0] : a2[gg][1];
      a1[gg] = keep + __shfl_xor(send, 4);
    }

    if (kq < 8) {
      const float r = 1.f / (1.f + expf(-(ir + a1[0] + br)));
      const float z = 1.f / (1.f + expf(-(iz + a1[1] + bz)));
      const float n = tanhf(inn + r * (a1[2] + bn2));
      const float hold = hl[ug * HSTRIDE + b_l];
      const float hnew = (1.f - z) * n + z * hold;
      hex[((size_t)(s & 1) * 8 + grp) * (8 * 512) + b_l * 512 + ug] = hnew;
      out[(size_t)((g * 8 + b_l) * Tn + t) * 1024 + d * DHn + ug] = hnew;
    }
    __syncthreads();   // drains each wave's stores to L2 before the release
    if (s < Tn - 1 && tid == 0)
      __hip_atomic_fetch_add(cnt, 1u, __ATOMIC_RELEASE, __HIP_MEMORY_SCOPE_AGENT);
  }
}

// ---------------- decoder: per-batch sequential argmax-feedback chain ----------------
__global__ __launch_bounds__(64) void decoder_kernel(
    const float* __restrict__ out_h,      // [B][T][1024]
    const float* __restrict__ label_emb,  // [10][25]
    const float* __restrict__ Wc,         // [9][1049]
    const float* __restrict__ bc,         // [9]
    float* __restrict__ out_chunk)        // [B*T][9]
{
  __shared__ float wcs[Cn * 1049];
  __shared__ float embs[(Cn + 1) * DEn];
  const int b = blockIdx.x;
  const int lane = threadIdx.x;
  for (int i = lane; i < Cn * 1049; i += 64) wcs[i] = Wc[i];
  for (int i = lane; i < (Cn + 1) * DEn; i += 64) embs[i] = label_emb[i];
  float bcv[Cn];
#pragma unroll
  for (int c = 0; c < Cn; c++) bcv[c] = bc[c];
  __syncthreads();

  int prev = Cn;  // start token
  for (int t = 0; t < Tn; t++) {
    const float* ht = out_h + (size_t)(b * Tn + t) * 1024;
    float hreg[16];
#pragma unroll
    for (int i = 0; i < 16; i++) hreg[i] = ht[lane + 64 * i];
    float acc[Cn];
#pragma unroll
    for (int c = 0; c < Cn; c++) {
      const float* wrow = &wcs[c * 1049];
      float a = 0.f;
#pragma unroll
      for (int i = 0; i < 16; i++) a = fmaf(hreg[i], wrow[lane + 64 * i], a);
      if (lane < DEn) a = fmaf(embs[prev * DEn + lane], wrow[1024 + lane], a);
      acc[c] = a;
    }
#pragma unroll
    for (int off = 32; off; off >>= 1)
#pragma unroll
      for (int c = 0; c < Cn; c++) acc[c] += __shfl_xor(acc[c], off);
#pragma unroll
    for (int c = 0; c < Cn; c++) acc[c] += bcv[c];
    float mx = acc[0]; int idx = 0;
#pragma unroll
    for (int c = 1; c < Cn; c++) if (acc[c] > mx) { mx = acc[c]; idx = c; }
    float e[Cn]; float sum = 0.f;
#pragma unroll
    for (int c = 0; c < Cn; c++) { e[c] = expf(acc[c] - mx); sum += e[c]; }
    float inv = 1.f / sum;
    if (lane < Cn) out_chunk[(size_t)(b * Tn + t) * Cn + lane] = e[lane] * inv;
    prev = idx;
  }
}

extern "C" void kernel_launch(void* const* d_in, const int* in_sizes, int n_in,
                              void* d_out, int out_size, void* d_ws, size_t ws_size,
                              hipStream_t stream) {
  const float* X      = (const float*)d_in[0];
  const float* pad    = (const float*)d_in[1];
  const float* lemb   = (const float*)d_in[2];
  const float* Wih_f  = (const float*)d_in[3];
  const float* Whh_f  = (const float*)d_in[4];
  const float* bih_f  = (const float*)d_in[5];
  const float* bhh_f  = (const float*)d_in[6];
  const float* Wih_b  = (const float*)d_in[7];
  const float* Whh_b  = (const float*)d_in[8];
  const float* bih_b  = (const float*)d_in[9];
  const float* bhh_b  = (const float*)d_in[10];
  const float* Wc     = (const float*)d_in[11];
  const float* bc     = (const float*)d_in[12];
  float* out = (float*)d_out;

  char* ws = (char*)d_ws;
  float*    gi   = (float*)ws;                                  // 100,663,296 B
  float*    Wp   = (float*)(ws + (size_t)MROW * NCOL * 4);      // 2*32*16*1540*4 = 6,307,840 B
  unsigned* sync = (unsigned*)(ws + (size_t)MROW * NCOL * 4 + 6307840);           // 1,024 B
  float*    hex  = (float*)(ws + (size_t)MROW * NCOL * 4 + 6307840 + 1024);       // 262,144 B

  prep_kernel<<<dim3(6144), dim3(256), 0, stream>>>(Whh_f, Whh_b, Wp, sync);
  gi_gemm_kernel<<<dim3(MROW / BM, NCOL / BN), dim3(256), 0, stream>>>(X, pad, Wih_f, Wih_b, bih_f, bih_b, gi);

  {
    void* args[] = {(void*)&gi, (void*)&Wp, (void*)&bhh_f, (void*)&bhh_b,
                    (void*)&sync, (void*)&hex, (void*)&out};
    hipLaunchCooperativeKernel((const void*)gru_rec3_kernel, dim3(256), dim3(256), args, 0, stream);
  }

  decoder_kernel<<<dim3(Bn), dim3(64), 0, stream>>>(out, lemb, Wc, bc, out + (size_t)MROW * 1024);
}

// Round 4
// 3308.349 us; speedup vs baseline: 6.1917x; 1.4830x over previous
//
#include <hip/hip_runtime.h>
#include <math.h>

#define Bn   32
#define Tn   256
#define DIN  768
#define DHn  512
#define DEn  25
#define Cn   9
#define K3   2304   // 3*DIN
#define H3   1536   // 3*DH
#define NCOL 3072   // 2*H3
#define MROW 8192   // B*T

// ---------------- gi pre-GEMM: gi[m][n] = lmr[m][:] . W[n][:] + bih[n] ----------------
#define BM 128
#define BN 128
#define BK 16

__global__ __launch_bounds__(256) void gi_gemm_kernel(
    const float* __restrict__ X, const float* __restrict__ pad,
    const float* __restrict__ Wf, const float* __restrict__ Wb,
    const float* __restrict__ bf, const float* __restrict__ bb,
    float* __restrict__ gi)
{
  __shared__ __align__(16) float As[BK][BM + 4];
  __shared__ __align__(16) float Bs[BK][BN + 4];
  const int bm = blockIdx.x, bn = blockIdx.y;
  const int tid = threadIdx.x;
  const int tx = tid & 15, ty = tid >> 4;
  const int m0 = bm * BM, n0 = bn * BN;
  const bool isF = (n0 < H3);
  const float* Wmat = isF ? Wf : Wb;
  const float* bias = isF ? bf : bb;
  const int nbase = isF ? n0 : (n0 - H3);

  float acc[8][8];
#pragma unroll
  for (int i = 0; i < 8; i++)
#pragma unroll
    for (int j = 0; j < 8; j++) acc[i][j] = 0.f;

  const int lrow = tid >> 2;       // 0..63
  const int lk = (tid & 3) * 4;    // 0,4,8,12

  for (int k0 = 0; k0 < K3; k0 += BK) {
#pragma unroll
    for (int i = 0; i < 2; i++) {
      int row = lrow + i * 64;
      int m = m0 + row;
      int b = m >> 8, t = m & 255;
      int kg = k0 + lk;
      int seg = (kg >= DIN) + (kg >= 2 * DIN);
      int off = kg - seg * DIN;
      int p = t + seg;                       // position in X_pad: 0..257
      float4 v;
      if (p == 0 || p == Tn + 1) v = *reinterpret_cast<const float4*>(pad + off);
      else v = *reinterpret_cast<const float4*>(X + (size_t)(b * Tn + (p - 1)) * DIN + off);
      As[lk + 0][row] = v.x; As[lk + 1][row] = v.y;
      As[lk + 2][row] = v.z; As[lk + 3][row] = v.w;
    }
#pragma unroll
    for (int i = 0; i < 2; i++) {
      int row = lrow + i * 64;
      const float* wp = Wmat + (size_t)(nbase + row) * K3 + k0 + lk;
      float4 v = *reinterpret_cast<const float4*>(wp);
      Bs[lk + 0][row] = v.x; Bs[lk + 1][row] = v.y;
      Bs[lk + 2][row] = v.z; Bs[lk + 3][row] = v.w;
    }
    __syncthreads();
#pragma unroll
    for (int kk = 0; kk < BK; kk++) {
      float4 a0 = *reinterpret_cast<const float4*>(&As[kk][ty * 8]);
      float4 a1 = *reinterpret_cast<const float4*>(&As[kk][ty * 8 + 4]);
      float4 b0 = *reinterpret_cast<const float4*>(&Bs[kk][tx * 8]);
      float4 b1 = *reinterpret_cast<const float4*>(&Bs[kk][tx * 8 + 4]);
      float av[8] = {a0.x, a0.y, a0.z, a0.w, a1.x, a1.y, a1.z, a1.w};
      float bv[8] = {b0.x, b0.y, b0.z, b0.w, b1.x, b1.y, b1.z, b1.w};
#pragma unroll
      for (int i = 0; i < 8; i++)
#pragma unroll
        for (int j = 0; j < 8; j++)
          acc[i][j] = fmaf(av[i], bv[j], acc[i][j]);
    }
    __syncthreads();
  }
#pragma unroll
  for (int i = 0; i < 8; i++) {
    int m = m0 + ty * 8 + i;
    float* orow = gi + (size_t)m * NCOL + n0 + tx * 8;
    float4 o0, o1;
    o0.x = acc[i][0] + bias[nbase + tx * 8 + 0];
    o0.y = acc[i][1] + bias[nbase + tx * 8 + 1];
    o0.z = acc[i][2] + bias[nbase + tx * 8 + 2];
    o0.w = acc[i][3] + bias[nbase + tx * 8 + 3];
    o1.x = acc[i][4] + bias[nbase + tx * 8 + 4];
    o1.y = acc[i][5] + bias[nbase + tx * 8 + 5];
    o1.z = acc[i][6] + bias[nbase + tx * 8 + 6];
    o1.w = acc[i][7] + bias[nbase + tx * 8 + 7];
    *reinterpret_cast<float4*>(orow) = o0;
    *reinterpret_cast<float4*>(orow + 4) = o1;
  }
}

// ---------------- prep: Wp[d][slice(32)][u(16)][k(512)] float4 {r,z,n,0} + zero sync ----------------
__global__ __launch_bounds__(256) void prep_kernel(
    const float* __restrict__ Whh_f, const float* __restrict__ Whh_b,
    float4* __restrict__ Wp, unsigned* __restrict__ sync)
{
  int f = blockIdx.x * 256 + threadIdx.x;    // 0 .. 524287
  if (f < 8) sync[f * 32] = 0u;
  if (f >= 2 * 32 * 16 * 512) return;
  int k   = f & 511;
  int u   = (f >> 9) & 15;
  int slc = (f >> 13) & 31;
  int d   = f >> 18;
  const float* Wsrc = d ? Whh_b : Whh_f;
  int ug = slc * 16 + u;
  float4 v;
  v.x = Wsrc[(size_t)(0 * DHn + ug) * DHn + k];
  v.y = Wsrc[(size_t)(1 * DHn + ug) * DHn + k];
  v.z = Wsrc[(size_t)(2 * DHn + ug) * DHn + k];
  v.w = 0.f;
  Wp[f] = v;
}

// ---------------- GRU recurrence: weights-stationary, MALL-routed exchange ----------------
// WG(bid): xcd=bid&7 -> d=xcd>>2, g=xcd&3 (sync group), slice=bid>>3.
// hex: [par(2)][grp(8)][u(512)][b(8)] floats (system-scope). sync: 8 counters, stride 32 dwords.
#define HSTRIDE 12     // dwords per k row of hl (8 batches + 4 pad; conflict-free b128 tiling)

__global__ __launch_bounds__(256) void gru_rec4_kernel(
    const float* __restrict__ gi,     // [8192][3072]
    const float4* __restrict__ Wp,    // [2][32][16][512] float4
    const float* __restrict__ bhh_f, const float* __restrict__ bhh_b,
    unsigned* __restrict__ sync,
    float* __restrict__ hex,
    float* __restrict__ out)          // [B][T][1024]
{
  __shared__ __align__(16) float4 Wl[16 * 512];       // 131,072 B
  __shared__ __align__(16) float hl[512 * HSTRIDE];   //  24,576 B

  const int bid = blockIdx.x;
  const int xcd = bid & 7;
  const int d = xcd >> 2, g = xcd & 3;
  const int sl = bid >> 3;                  // unit slice 0..31
  const int tid = threadIdx.x;
  const int ut = tid >> 4;                  // unit-local 0..15
  const int kq = tid & 15;                  // k-slice 0..15
  const int grp = d * 4 + g;

  // stage weights (once, coalesced float4)
  {
    const float4* src = Wp + (size_t)(d * 32 + sl) * 8192;
    for (int i = tid; i < 8192; i += 256) Wl[i] = src[i];
  }
  for (int i = tid; i < 512 * HSTRIDE; i += 256) hl[i] = 0.f;

  const float* bhh = d ? bhh_b : bhh_f;
  const int ug = sl * 16 + ut;              // this thread's output unit (0..511)
  const float br = bhh[ug], bz = bhh[DHn + ug], bn2 = bhh[2 * DHn + ug];
  const int b_l = ((kq & 1) << 2) | (kq & 2) | ((kq >> 2) & 1);  // reduce-scatter owner batch

  unsigned* cnt = sync + grp * 32;

  __syncthreads();

  for (int s = 0; s < Tn; s++) {
    const int t = d ? (Tn - 1 - s) : s;

    // gi prefetch: independent of the exchange — issue BEFORE the poll so
    // MALL/HBM latency hides under the wait.
    float ir = 0.f, iz = 0.f, inn = 0.f;
    if (kq < 8) {
      const int bg = g * 8 + b_l;
      const float* gp = gi + (size_t)(bg * Tn + t) * NCOL + d * H3 + ug;
      ir = gp[0]; iz = gp[DHn]; inn = gp[2 * DHn];
    }

    if (s > 0) {
      if (tid == 0) {
        const unsigned tgt = 32u * (unsigned)s;
        while (__hip_atomic_load(cnt, __ATOMIC_RELAXED, __HIP_MEMORY_SCOPE_SYSTEM) < tgt)
          __builtin_amdgcn_s_sleep(1);
      }
      __syncthreads();
      asm volatile("" ::: "memory");   // compiler fence: keep data loads after the poll
      // readback h(s-1): u-major system-scope u64 loads -> aligned b64 LDS writes
      const uint64_t* src = reinterpret_cast<const uint64_t*>(
          hex + (size_t)(((s - 1) & 1) * 8 + grp) * (512 * 8));
#pragma unroll
      for (int j = 0; j < 8; j++) {
        uint64_t v = __hip_atomic_load(src + tid + 256 * j,
                                       __ATOMIC_RELAXED, __HIP_MEMORY_SCOPE_SYSTEM);
        int fd = 2 * (tid + 256 * j);
        int u = fd >> 3, b = fd & 7;          // b even
        *reinterpret_cast<uint64_t*>(&hl[u * HSTRIDE + b]) = v;
      }
      __syncthreads();
    }

    float acc[3][8];
#pragma unroll
    for (int gg = 0; gg < 3; gg++)
#pragma unroll
      for (int bb = 0; bb < 8; bb++) acc[gg][bb] = 0.f;

#pragma unroll 4
    for (int i = 0; i < 32; i++) {
      int k = i * 16 + kq;
      float4 wv = Wl[ut * 512 + k];           // {r,z,n,pad} one b128, conflict-free
      const float* hp = &hl[k * HSTRIDE];
      float4 ha = *reinterpret_cast<const float4*>(hp);
      float4 hb = *reinterpret_cast<const float4*>(hp + 4);
      acc[0][0] = fmaf(wv.x, ha.x, acc[0][0]); acc[0][1] = fmaf(wv.x, ha.y, acc[0][1]);
      acc[0][2] = fmaf(wv.x, ha.z, acc[0][2]); acc[0][3] = fmaf(wv.x, ha.w, acc[0][3]);
      acc[0][4] = fmaf(wv.x, hb.x, acc[0][4]); acc[0][5] = fmaf(wv.x, hb.y, acc[0][5]);
      acc[0][6] = fmaf(wv.x, hb.z, acc[0][6]); acc[0][7] = fmaf(wv.x, hb.w, acc[0][7]);
      acc[1][0] = fmaf(wv.y, ha.x, acc[1][0]); acc[1][1] = fmaf(wv.y, ha.y, acc[1][1]);
      acc[1][2] = fmaf(wv.y, ha.z, acc[1][2]); acc[1][3] = fmaf(wv.y, ha.w, acc[1][3]);
      acc[1][4] = fmaf(wv.y, hb.x, acc[1][4]); acc[1][5] = fmaf(wv.y, hb.y, acc[1][5]);
      acc[1][6] = fmaf(wv.y, hb.z, acc[1][6]); acc[1][7] = fmaf(wv.y, hb.w, acc[1][7]);
      acc[2][0] = fmaf(wv.z, ha.x, acc[2][0]); acc[2][1] = fmaf(wv.z, ha.y, acc[2][1]);
      acc[2][2] = fmaf(wv.z, ha.z, acc[2][2]); acc[2][3] = fmaf(wv.z, ha.w, acc[2][3]);
      acc[2][4] = fmaf(wv.z, hb.x, acc[2][4]); acc[2][5] = fmaf(wv.z, hb.y, acc[2][5]);
      acc[2][6] = fmaf(wv.z, hb.z, acc[2][6]); acc[2][7] = fmaf(wv.z, hb.w, acc[2][7]);
    }

    // mask-8 full add: pair {kq, kq+8}
#pragma unroll
    for (int gg = 0; gg < 3; gg++)
#pragma unroll
      for (int bb = 0; bb < 8; bb++)
        acc[gg][bb] += __shfl_xor(acc[gg][bb], 8);

    // reduce-scatter masks 1,2,4 (all compile-time indices)
    float a4[3][4];
#pragma unroll
    for (int gg = 0; gg < 3; gg++)
#pragma unroll
      for (int j = 0; j < 4; j++) {
        float keep = (kq & 1) ? acc[gg][4 + j] : acc[gg][j];
        float send = (kq & 1) ? acc[gg][j] : acc[gg][4 + j];
        a4[gg][j] = keep + __shfl_xor(send, 1);
      }
    float a2[3][2];
#pragma unroll
    for (int gg = 0; gg < 3; gg++)
#pragma unroll
      for (int j = 0; j < 2; j++) {
        float keep = (kq & 2) ? a4[gg][2 + j] : a4[gg][j];
        float send = (kq & 2) ? a4[gg][j] : a4[gg][2 + j];
        a2[gg][j] = keep + __shfl_xor(send, 2);
      }
    float a1[3];
#pragma unroll
    for (int gg = 0; gg < 3; gg++) {
      float keep = (kq & 4) ? a2[gg][1] : a2[gg][0];
      float send = (kq & 4) ? a2[gg][0] : a2[gg][1];
      a1[gg] = keep + __shfl_xor(send, 4);
    }

    if (kq < 8) {
      const float r = 1.f / (1.f + expf(-(ir + a1[0] + br)));
      const float z = 1.f / (1.f + expf(-(iz + a1[1] + bz)));
      const float n = tanhf(inn + r * (a1[2] + bn2));
      const float hold = hl[ug * HSTRIDE + b_l];
      const float hnew = (1.f - z) * n + z * hold;
      // system-scope (MALL) store: visible to peer XCDs without cache maintenance
      __hip_atomic_store(&hex[((size_t)(s & 1) * 8 + grp) * (512 * 8) + ug * 8 + b_l],
                         hnew, __ATOMIC_RELAXED, __HIP_MEMORY_SCOPE_SYSTEM);
      out[(size_t)((g * 8 + b_l) * Tn + t) * 1024 + d * DHn + ug] = hnew;
    }
    // __syncthreads() drains each wave's vmcnt(0) -> all hex stores MALL-complete
    __syncthreads();
    if (s < Tn - 1 && tid == 0)
      __hip_atomic_fetch_add(cnt, 1u, __ATOMIC_RELAXED, __HIP_MEMORY_SCOPE_SYSTEM);
  }
}

// ---------------- decoder: per-batch sequential argmax-feedback chain ----------------
__global__ __launch_bounds__(64) void decoder_kernel(
    const float* __restrict__ out_h,      // [B][T][1024]
    const float* __restrict__ label_emb,  // [10][25]
    const float* __restrict__ Wc,         // [9][1049]
    const float* __restrict__ bc,         // [9]
    float* __restrict__ out_chunk)        // [B*T][9]
{
  __shared__ float wcs[Cn * 1049];
  __shared__ float embs[(Cn + 1) * DEn];
  const int b = blockIdx.x;
  const int lane = threadIdx.x;
  for (int i = lane; i < Cn * 1049; i += 64) wcs[i] = Wc[i];
  for (int i = lane; i < (Cn + 1) * DEn; i += 64) embs[i] = label_emb[i];
  float bcv[Cn];
#pragma unroll
  for (int c = 0; c < Cn; c++) bcv[c] = bc[c];
  __syncthreads();

  int prev = Cn;  // start token
  for (int t = 0; t < Tn; t++) {
    const float* ht = out_h + (size_t)(b * Tn + t) * 1024;
    float hreg[16];
#pragma unroll
    for (int i = 0; i < 16; i++) hreg[i] = ht[lane + 64 * i];
    float acc[Cn];
#pragma unroll
    for (int c = 0; c < Cn; c++) {
      const float* wrow = &wcs[c * 1049];
      float a = 0.f;
#pragma unroll
      for (int i = 0; i < 16; i++) a = fmaf(hreg[i], wrow[lane + 64 * i], a);
      if (lane < DEn) a = fmaf(embs[prev * DEn + lane], wrow[1024 + lane], a);
      acc[c] = a;
    }
#pragma unroll
    for (int off = 32; off; off >>= 1)
#pragma unroll
      for (int c = 0; c < Cn; c++) acc[c] += __shfl_xor(acc[c], off);
#pragma unroll
    for (int c = 0; c < Cn; c++) acc[c] += bcv[c];
    float mx = acc[0]; int idx = 0;
#pragma unroll
    for (int c = 1; c < Cn; c++) if (acc[c] > mx) { mx = acc[c]; idx = c; }
    float e[Cn]; float sum = 0.f;
#pragma unroll
    for (int c = 0; c < Cn; c++) { e[c] = expf(acc[c] - mx); sum += e[c]; }
    float inv = 1.f / sum;
    if (lane < Cn) out_chunk[(size_t)(b * Tn + t) * Cn + lane] = e[lane] * inv;
    prev = idx;
  }
}

extern "C" void kernel_launch(void* const* d_in, const int* in_sizes, int n_in,
                              void* d_out, int out_size, void* d_ws, size_t ws_size,
                              hipStream_t stream) {
  const float* X      = (const float*)d_in[0];
  const float* pad    = (const float*)d_in[1];
  const float* lemb   = (const float*)d_in[2];
  const float* Wih_f  = (const float*)d_in[3];
  const float* Whh_f  = (const float*)d_in[4];
  const float* bih_f  = (const float*)d_in[5];
  const float* bhh_f  = (const float*)d_in[6];
  const float* Wih_b  = (const float*)d_in[7];
  const float* Whh_b  = (const float*)d_in[8];
  const float* bih_b  = (const float*)d_in[9];
  const float* bhh_b  = (const float*)d_in[10];
  const float* Wc     = (const float*)d_in[11];
  const float* bc     = (const float*)d_in[12];
  float* out = (float*)d_out;

  char* ws = (char*)d_ws;
  float*    gi   = (float*)ws;                                  // 100,663,296 B
  float4*   Wp   = (float4*)(ws + (size_t)MROW * NCOL * 4);     // 2*32*16*512*16 = 8,388,608 B
  unsigned* sync = (unsigned*)(ws + (size_t)MROW * NCOL * 4 + 8388608);           // 1,024 B
  float*    hex  = (float*)(ws + (size_t)MROW * NCOL * 4 + 8388608 + 1024);       // 262,144 B

  prep_kernel<<<dim3(2048), dim3(256), 0, stream>>>(Whh_f, Whh_b, Wp, sync);
  gi_gemm_kernel<<<dim3(MROW / BM, NCOL / BN), dim3(256), 0, stream>>>(X, pad, Wih_f, Wih_b, bih_f, bih_b, gi);
  gru_rec4_kernel<<<dim3(256), dim3(256), 0, stream>>>(gi, Wp, bhh_f, bhh_b, sync, hex, out);
  decoder_kernel<<<dim3(Bn), dim3(64), 0, stream>>>(out, lemb, Wc, bc, out + (size_t)MROW * 1024);
}

// Round 6
// 2107.719 us; speedup vs baseline: 9.7187x; 1.5696x over previous
//
#include <hip/hip_runtime.h>
#include <hip/hip_bf16.h>
#include <math.h>

#define Bn   32
#define Tn   256
#define DIN  768
#define DHn  512
#define DEn  25
#define Cn   9
#define K3   2304   // 3*DIN
#define H3   1536   // 3*DH
#define NCOL 3072   // 2*H3
#define MROW 8192   // B*T

typedef __attribute__((ext_vector_type(8))) short short8v;
typedef __attribute__((ext_vector_type(4))) float f32x4;

__device__ __forceinline__ unsigned short f2bf(float v) {
  __hip_bfloat16 h = __float2bfloat16(v);
  return __builtin_bit_cast(unsigned short, h);
}
__device__ __forceinline__ float bf2f(unsigned short u) {
  return __bfloat162float(__builtin_bit_cast(__hip_bfloat16, u));
}

// ---------------- gi pre-GEMM via bf16x3-split MFMA ----------------
// gi[m][n] = lmr[m][:] . W[n][:] + bih[n]; M=8192, N=3072, K=2304.
#define GBM 128
#define GBN 128
#define GBK 32
#define ASTR 40   // shorts per LDS row (32 + 8 pad): stride 80B -> conflict-free b128

__global__ __launch_bounds__(256) void gi_gemm_mfma_kernel(
    const float* __restrict__ X, const float* __restrict__ pad,
    const float* __restrict__ Wf, const float* __restrict__ Wb,
    const float* __restrict__ bf, const float* __restrict__ bb,
    float* __restrict__ gi)
{
  __shared__ __align__(16) unsigned short Ah[GBM * ASTR];
  __shared__ __align__(16) unsigned short Al[GBM * ASTR];
  __shared__ __align__(16) unsigned short Bh[GBN * ASTR];
  __shared__ __align__(16) unsigned short Bl[GBN * ASTR];

  const int bnb = blockIdx.x;          // n-block 0..23  (x fast => A-tile L2 reuse)
  const int bmb = blockIdx.y;          // m-block 0..63
  const int tid = threadIdx.x;
  const int m0 = bmb * GBM, n0 = bnb * GBN;
  const bool isF = (n0 < H3);
  const float* Wmat = isF ? Wf : Wb;
  const float* bias = isF ? bf : bb;
  const int nb0 = isF ? n0 : (n0 - H3);

  // staging role: each thread owns row r (A and B), k-half
  const int r = tid >> 1, half = tid & 1;
  const int m = m0 + r;
  const int ab = m >> 8, tpos = m & 255;
  const float* wrowp = Wmat + (size_t)(nb0 + r) * K3;

  // mfma role
  const int wave = tid >> 6, lane = tid & 63;
  const int wr = wave >> 1, wc = wave & 1;
  const int lrow = lane & 15, lk = (lane >> 4) * 8;

  f32x4 acc[4][4];
#pragma unroll
  for (int i = 0; i < 4; i++)
#pragma unroll
    for (int j = 0; j < 4; j++) acc[i][j] = (f32x4){0.f, 0.f, 0.f, 0.f};

  for (int k0 = 0; k0 < K3; k0 += GBK) {
    // ---- stage A (virtual trigram lmr) and B (Wih rows), split hi/lo bf16 ----
#pragma unroll
    for (int j2 = 0; j2 < 2; j2++) {
      const int kg = k0 + half * 16 + j2 * 8;
      // A: segment never crossed within an aligned 8-run (768 % 8 == 0)
      const int seg = (kg >= DIN) + (kg >= 2 * DIN);
      const int off = kg - seg * DIN;
      const int p = tpos + seg;
      const float* srcA = (p == 0 || p == Tn + 1)
                            ? (pad + off)
                            : (X + (size_t)(ab * Tn + (p - 1)) * DIN + off);
      float4 a0 = *reinterpret_cast<const float4*>(srcA);
      float4 a1 = *reinterpret_cast<const float4*>(srcA + 4);
      const float* srcB = wrowp + kg;
      float4 b0 = *reinterpret_cast<const float4*>(srcB);
      float4 b1 = *reinterpret_cast<const float4*>(srcB + 4);

      float av[8] = {a0.x, a0.y, a0.z, a0.w, a1.x, a1.y, a1.z, a1.w};
      float bv[8] = {b0.x, b0.y, b0.z, b0.w, b1.x, b1.y, b1.z, b1.w};
      short8v ah8, al8, bh8, bl8;
#pragma unroll
      for (int q = 0; q < 8; q++) {
        unsigned short h = f2bf(av[q]);
        ah8[q] = (short)h;
        al8[q] = (short)f2bf(av[q] - bf2f(h));
        unsigned short g = f2bf(bv[q]);
        bh8[q] = (short)g;
        bl8[q] = (short)f2bf(bv[q] - bf2f(g));
      }
      const int si = r * ASTR + half * 16 + j2 * 8;
      *reinterpret_cast<short8v*>(&Ah[si]) = ah8;
      *reinterpret_cast<short8v*>(&Al[si]) = al8;
      *reinterpret_cast<short8v*>(&Bh[si]) = bh8;
      *reinterpret_cast<short8v*>(&Bl[si]) = bl8;
    }
    __syncthreads();

    // ---- fragments + 48 MFMA (3 split terms x 4x4 tiles) ----
    short8v fah[4], fal[4], fbh[4], fbl[4];
#pragma unroll
    for (int i = 0; i < 4; i++) {
      const int ai = (wr * 64 + i * 16 + lrow) * ASTR + lk;
      const int bi = (wc * 64 + i * 16 + lrow) * ASTR + lk;
      fah[i] = *reinterpret_cast<const short8v*>(&Ah[ai]);
      fal[i] = *reinterpret_cast<const short8v*>(&Al[ai]);
      fbh[i] = *reinterpret_cast<const short8v*>(&Bh[bi]);
      fbl[i] = *reinterpret_cast<const short8v*>(&Bl[bi]);
    }
#pragma unroll
    for (int mi = 0; mi < 4; mi++)
#pragma unroll
      for (int ni = 0; ni < 4; ni++) {
        acc[mi][ni] = __builtin_amdgcn_mfma_f32_16x16x32_bf16(fah[mi], fbh[ni], acc[mi][ni], 0, 0, 0);
        acc[mi][ni] = __builtin_amdgcn_mfma_f32_16x16x32_bf16(fah[mi], fbl[ni], acc[mi][ni], 0, 0, 0);
        acc[mi][ni] = __builtin_amdgcn_mfma_f32_16x16x32_bf16(fal[mi], fbh[ni], acc[mi][ni], 0, 0, 0);
      }
    __syncthreads();
  }

  // ---- epilogue: + bih, store fp32 (C map: col=lane&15, row=(lane>>4)*4+reg) ----
#pragma unroll
  for (int ni = 0; ni < 4; ni++) {
    const int nl = wc * 64 + ni * 16 + (lane & 15);
    const float bvv = bias[nb0 + nl];
#pragma unroll
    for (int mi = 0; mi < 4; mi++) {
      const int mg = m0 + wr * 64 + mi * 16 + (lane >> 4) * 4;
#pragma unroll
      for (int reg = 0; reg < 4; reg++)
        gi[(size_t)(mg + reg) * NCOL + n0 + nl] = acc[mi][ni][reg] + bvv;
    }
  }
}

// ---------------- prep: Wp[d][slice(32)][u(16)][k(512)] float4 {r,z,n,0} + zero sync ----------------
__global__ __launch_bounds__(256) void prep_kernel(
    const float* __restrict__ Whh_f, const float* __restrict__ Whh_b,
    float4* __restrict__ Wp, unsigned* __restrict__ sync)
{
  int f = blockIdx.x * 256 + threadIdx.x;    // 0 .. 524287
  if (f < 8) sync[f * 32] = 0u;
  if (f >= 2 * 32 * 16 * 512) return;
  int k   = f & 511;
  int u   = (f >> 9) & 15;
  int slc = (f >> 13) & 31;
  int d   = f >> 18;
  const float* Wsrc = d ? Whh_b : Whh_f;
  int ug = slc * 16 + u;
  float4 v;
  v.x = Wsrc[(size_t)(0 * DHn + ug) * DHn + k];
  v.y = Wsrc[(size_t)(1 * DHn + ug) * DHn + k];
  v.z = Wsrc[(size_t)(2 * DHn + ug) * DHn + k];
  v.w = 0.f;
  Wp[f] = v;
}

// ---------------- etab[p][c] = emb[p] . Wc[c][1024:1049] ----------------
__global__ __launch_bounds__(128) void etab_kernel(
    const float* __restrict__ label_emb, const float* __restrict__ Wc,
    float* __restrict__ etab)
{
  int t = threadIdx.x;
  if (t >= 90) return;
  int p = t / Cn, c = t % Cn;
  float a = 0.f;
#pragma unroll
  for (int j = 0; j < DEn; j++)
    a = fmaf(label_emb[p * DEn + j], Wc[(size_t)c * 1049 + 1024 + j], a);
  etab[t] = a;
}

// ---------------- GRU recurrence: weights-stationary, MALL-routed exchange ----------------
#define HSTRIDE 12

__global__ __launch_bounds__(256) void gru_rec4_kernel(
    const float* __restrict__ gi,     // [8192][3072]
    const float4* __restrict__ Wp,    // [2][32][16][512] float4
    const float* __restrict__ bhh_f, const float* __restrict__ bhh_b,
    unsigned* __restrict__ sync,
    float* __restrict__ hex,
    float* __restrict__ out)          // [B][T][1024]
{
  __shared__ __align__(16) float4 Wl[16 * 512];       // 131,072 B
  __shared__ __align__(16) float hl[512 * HSTRIDE];   //  24,576 B

  const int bid = blockIdx.x;
  const int xcd = bid & 7;
  const int d = xcd >> 2, g = xcd & 3;
  const int sl = bid >> 3;
  const int tid = threadIdx.x;
  const int ut = tid >> 4;
  const int kq = tid & 15;
  const int grp = d * 4 + g;

  {
    const float4* src = Wp + (size_t)(d * 32 + sl) * 8192;
    for (int i = tid; i < 8192; i += 256) Wl[i] = src[i];
  }
  for (int i = tid; i < 512 * HSTRIDE; i += 256) hl[i] = 0.f;

  const float* bhh = d ? bhh_b : bhh_f;
  const int ug = sl * 16 + ut;
  const float br = bhh[ug], bz = bhh[DHn + ug], bn2 = bhh[2 * DHn + ug];
  const int b_l = ((kq & 1) << 2) | (kq & 2) | ((kq >> 2) & 1);

  unsigned* cnt = sync + grp * 32;

  __syncthreads();

  for (int s = 0; s < Tn; s++) {
    const int t = d ? (Tn - 1 - s) : s;

    float ir = 0.f, iz = 0.f, inn = 0.f;
    if (kq < 8) {
      const int bg = g * 8 + b_l;
      const float* gp = gi + (size_t)(bg * Tn + t) * NCOL + d * H3 + ug;
      ir = gp[0]; iz = gp[DHn]; inn = gp[2 * DHn];
    }

    if (s > 0) {
      if (tid == 0) {
        const unsigned tgt = 32u * (unsigned)s;
        while (__hip_atomic_load(cnt, __ATOMIC_RELAXED, __HIP_MEMORY_SCOPE_SYSTEM) < tgt)
          __builtin_amdgcn_s_sleep(1);
      }
      __syncthreads();
      asm volatile("" ::: "memory");
      const uint64_t* src = reinterpret_cast<const uint64_t*>(
          hex + (size_t)(((s - 1) & 1) * 8 + grp) * (512 * 8));
#pragma unroll
      for (int j = 0; j < 8; j++) {
        uint64_t v = __hip_atomic_load(src + tid + 256 * j,
                                       __ATOMIC_RELAXED, __HIP_MEMORY_SCOPE_SYSTEM);
        int fd = 2 * (tid + 256 * j);
        int u = fd >> 3, b = fd & 7;
        *reinterpret_cast<uint64_t*>(&hl[u * HSTRIDE + b]) = v;
      }
      __syncthreads();
    }

    float acc[3][8];
#pragma unroll
    for (int gg = 0; gg < 3; gg++)
#pragma unroll
      for (int bb = 0; bb < 8; bb++) acc[gg][bb] = 0.f;

#pragma unroll 4
    for (int i = 0; i < 32; i++) {
      int k = i * 16 + kq;
      float4 wv = Wl[ut * 512 + k];
      const float* hp = &hl[k * HSTRIDE];
      float4 ha = *reinterpret_cast<const float4*>(hp);
      float4 hb = *reinterpret_cast<const float4*>(hp + 4);
      acc[0][0] = fmaf(wv.x, ha.x, acc[0][0]); acc[0][1] = fmaf(wv.x, ha.y, acc[0][1]);
      acc[0][2] = fmaf(wv.x, ha.z, acc[0][2]); acc[0][3] = fmaf(wv.x, ha.w, acc[0][3]);
      acc[0][4] = fmaf(wv.x, hb.x, acc[0][4]); acc[0][5] = fmaf(wv.x, hb.y, acc[0][5]);
      acc[0][6] = fmaf(wv.x, hb.z, acc[0][6]); acc[0][7] = fmaf(wv.x, hb.w, acc[0][7]);
      acc[1][0] = fmaf(wv.y, ha.x, acc[1][0]); acc[1][1] = fmaf(wv.y, ha.y, acc[1][1]);
      acc[1][2] = fmaf(wv.y, ha.z, acc[1][2]); acc[1][3] = fmaf(wv.y, ha.w, acc[1][3]);
      acc[1][4] = fmaf(wv.y, hb.x, acc[1][4]); acc[1][5] = fmaf(wv.y, hb.y, acc[1][5]);
      acc[1][6] = fmaf(wv.y, hb.z, acc[1][6]); acc[1][7] = fmaf(wv.y, hb.w, acc[1][7]);
      acc[2][0] = fmaf(wv.z, ha.x, acc[2][0]); acc[2][1] = fmaf(wv.z, ha.y, acc[2][1]);
      acc[2][2] = fmaf(wv.z, ha.z, acc[2][2]); acc[2][3] = fmaf(wv.z, ha.w, acc[2][3]);
      acc[2][4] = fmaf(wv.z, hb.x, acc[2][4]); acc[2][5] = fmaf(wv.z, hb.y, acc[2][5]);
      acc[2][6] = fmaf(wv.z, hb.z, acc[2][6]); acc[2][7] = fmaf(wv.z, hb.w, acc[2][7]);
    }

#pragma unroll
    for (int gg = 0; gg < 3; gg++)
#pragma unroll
      for (int bb = 0; bb < 8; bb++)
        acc[gg][bb] += __shfl_xor(acc[gg][bb], 8);

    float a4[3][4];
#pragma unroll
    for (int gg = 0; gg < 3; gg++)
#pragma unroll
      for (int j = 0; j < 4; j++) {
        float keep = (kq & 1) ? acc[gg][4 + j] : acc[gg][j];
        float send = (kq & 1) ? acc[gg][j] : acc[gg][4 + j];
        a4[gg][j] = keep + __shfl_xor(send, 1);
      }
    float a2[3][2];
#pragma unroll
    for (int gg = 0; gg < 3; gg++)
#pragma unroll
      for (int j = 0; j < 2; j++) {
        float keep = (kq & 2) ? a4[gg][2 + j] : a4[gg][j];
        float send = (kq & 2) ? a4[gg][j] : a4[gg][2 + j];
        a2[gg][j] = keep + __shfl_xor(send, 2);
      }
    float a1[3];
#pragma unroll
    for (int gg = 0; gg < 3; gg++) {
      float keep = (kq & 4) ? a2[gg][1] : a2[gg][0];
      float send = (kq & 4) ? a2[gg][0] : a2[gg][1];
      a1[gg] = keep + __shfl_xor(send, 4);
    }

    if (kq < 8) {
      const float r = 1.f / (1.f + expf(-(ir + a1[0] + br)));
      const float z = 1.f / (1.f + expf(-(iz + a1[1] + bz)));
      const float n = tanhf(inn + r * (a1[2] + bn2));
      const float hold = hl[ug * HSTRIDE + b_l];
      const float hnew = (1.f - z) * n + z * hold;
      __hip_atomic_store(&hex[((size_t)(s & 1) * 8 + grp) * (512 * 8) + ug * 8 + b_l],
                         hnew, __ATOMIC_RELAXED, __HIP_MEMORY_SCOPE_SYSTEM);
      out[(size_t)((g * 8 + b_l) * Tn + t) * 1024 + d * DHn + ug] = hnew;
    }
    __syncthreads();
    if (s < Tn - 1 && tid == 0)
      __hip_atomic_fetch_add(cnt, 1u, __ATOMIC_RELAXED, __HIP_MEMORY_SCOPE_SYSTEM);
  }
}

// ---------------- lh[b*T+t][c] = h . Wc[c][:1024] + bc[c]  (feedback-free part) ----------------
__global__ __launch_bounds__(256) void lh_kernel(
    const float* __restrict__ out_h, const float* __restrict__ Wc,
    const float* __restrict__ bc, float* __restrict__ lh)
{
  const int tid = threadIdx.x;
  const int wave = tid >> 6, lane = tid & 63;
#pragma unroll 1
  for (int it = 0; it < 16; it++) {
    const int row = blockIdx.x * 64 + wave * 16 + it;
    const float* hp = out_h + (size_t)row * 1024 + lane * 4;
    float4 hv[4];
#pragma unroll
    for (int j = 0; j < 4; j++) hv[j] = *reinterpret_cast<const float4*>(hp + 256 * j);
    float acc[Cn];
#pragma unroll
    for (int c = 0; c < Cn; c++) {
      const float* wp = Wc + (size_t)c * 1049 + lane * 4;
      float a = 0.f;
#pragma unroll
      for (int j = 0; j < 4; j++) {
        float4 wv = *reinterpret_cast<const float4*>(wp + 256 * j);
        a = fmaf(hv[j].x, wv.x, a); a = fmaf(hv[j].y, wv.y, a);
        a = fmaf(hv[j].z, wv.z, a); a = fmaf(hv[j].w, wv.w, a);
      }
      acc[c] = a;
    }
#pragma unroll
    for (int off = 32; off; off >>= 1)
#pragma unroll
      for (int c = 0; c < Cn; c++) acc[c] += __shfl_xor(acc[c], off);
    if (lane < Cn) lh[(size_t)row * 12 + lane] = acc[lane] + bc[lane];
  }
}

// ---------------- chain: per-batch argmax feedback, 9 adds/step ----------------
__global__ __launch_bounds__(64) void chain_kernel(
    const float* __restrict__ lh,   // [8192][12]
    const float* __restrict__ etab, // [10][9]
    float* __restrict__ outc)       // [8192][9]
{
  __shared__ float et[90];
  const int tid = threadIdx.x;
  if (tid < 90) et[tid] = etab[tid];
  __syncthreads();
  if (tid >= Bn) return;
  const int b = tid;
  const float* base = lh + (size_t)b * Tn * 12;
  float4 A0 = *reinterpret_cast<const float4*>(base);
  float4 A1 = *reinterpret_cast<const float4*>(base + 4);
  float c8 = base[8];
  int prev = Cn;
  for (int t = 0; t < Tn; t++) {
    float4 N0 = {0,0,0,0}, N1 = {0,0,0,0}; float nc8 = 0.f;
    if (t < Tn - 1) {
      const float* nb = base + (size_t)(t + 1) * 12;
      N0 = *reinterpret_cast<const float4*>(nb);
      N1 = *reinterpret_cast<const float4*>(nb + 4);
      nc8 = nb[8];
    }
    float lg[Cn] = {A0.x, A0.y, A0.z, A0.w, A1.x, A1.y, A1.z, A1.w, c8};
    const float* ep = &et[prev * Cn];
#pragma unroll
    for (int c = 0; c < Cn; c++) lg[c] += ep[c];
    float mx = lg[0]; int idx = 0;
#pragma unroll
    for (int c = 1; c < Cn; c++) if (lg[c] > mx) { mx = lg[c]; idx = c; }
    float e[Cn]; float sum = 0.f;
#pragma unroll
    for (int c = 0; c < Cn; c++) { e[c] = expf(lg[c] - mx); sum += e[c]; }
    const float inv = 1.f / sum;
    float* op = outc + ((size_t)b * Tn + t) * Cn;
#pragma unroll
    for (int c = 0; c < Cn; c++) op[c] = e[c] * inv;
    prev = idx;
    A0 = N0; A1 = N1; c8 = nc8;
  }
}

extern "C" void kernel_launch(void* const* d_in, const int* in_sizes, int n_in,
                              void* d_out, int out_size, void* d_ws, size_t ws_size,
                              hipStream_t stream) {
  const float* X      = (const float*)d_in[0];
  const float* pad    = (const float*)d_in[1];
  const float* lemb   = (const float*)d_in[2];
  const float* Wih_f  = (const float*)d_in[3];
  const float* Whh_f  = (const float*)d_in[4];
  const float* bih_f  = (const float*)d_in[5];
  const float* bhh_f  = (const float*)d_in[6];
  const float* Wih_b  = (const float*)d_in[7];
  const float* Whh_b  = (const float*)d_in[8];
  const float* bih_b  = (const float*)d_in[9];
  const float* bhh_b  = (const float*)d_in[10];
  const float* Wc     = (const float*)d_in[11];
  const float* bc     = (const float*)d_in[12];
  float* out = (float*)d_out;

  char* ws = (char*)d_ws;
  float*    gi   = (float*)ws;                                  // 100,663,296 B
  float4*   Wp   = (float4*)(ws + (size_t)MROW * NCOL * 4);     // 8,388,608 B
  unsigned* sync = (unsigned*)(ws + (size_t)MROW * NCOL * 4 + 8388608);      // 1,024 B
  float*    hex  = (float*)(ws + (size_t)MROW * NCOL * 4 + 8388608 + 1024);  // 262,144 B
  // lh + etab overlap the (dead-after-gru) gi region; etab_kernel runs AFTER gru.
  float*    lh   = (float*)ws;                                  // 393,216 B
  float*    etab = (float*)(ws + 524288);                       // 360 B

  prep_kernel<<<dim3(2048), dim3(256), 0, stream>>>(Whh_f, Whh_b, Wp, sync);
  gi_gemm_mfma_kernel<<<dim3(NCOL / GBN, MROW / GBM), dim3(256), 0, stream>>>(
      X, pad, Wih_f, Wih_b, bih_f, bih_b, gi);
  gru_rec4_kernel<<<dim3(256), dim3(256), 0, stream>>>(gi, Wp, bhh_f, bhh_b, sync, hex, out);
  etab_kernel<<<dim3(1), dim3(128), 0, stream>>>(lemb, Wc, etab);   // after gru: gi region dead
  lh_kernel<<<dim3(128), dim3(256), 0, stream>>>(out, Wc, bc, lh);
  chain_kernel<<<dim3(1), dim3(64), 0, stream>>>(lh, etab, out + (size_t)MROW * 1024);
}

// Round 7
// 1917.889 us; speedup vs baseline: 10.6807x; 1.0990x over previous
//
#include <hip/hip_runtime.h>
#include <hip/hip_bf16.h>
#include <math.h>

#define Bn   32
#define Tn   256
#define DIN  768
#define DHn  512
#define DEn  25
#define Cn   9
#define K3   2304   // 3*DIN
#define H3   1536   // 3*DH
#define NCOL 3072   // 2*H3
#define MROW 8192   // B*T

typedef __attribute__((ext_vector_type(8))) short short8v;
typedef __attribute__((ext_vector_type(4))) float f32x4;

__device__ __forceinline__ unsigned short f2bf(float v) {
  __hip_bfloat16 h = __float2bfloat16(v);
  return __builtin_bit_cast(unsigned short, h);
}
__device__ __forceinline__ float bf2f(unsigned short u) {
  return __bfloat162float(__builtin_bit_cast(__hip_bfloat16, u));
}

// ---------------- gi pre-GEMM via bf16x3-split MFMA ----------------
// gi[m][n] = lmr[m][:] . W[n][:] + bih[n]; M=8192, N=3072, K=2304.
#define GBM 128
#define GBN 128
#define GBK 64
#define ASTR 72   // shorts per LDS row (64 + 8 pad): rows advance 4 banks -> <=2-way (free)

__global__ __launch_bounds__(256) void gi_gemm_mfma_kernel(
    const float* __restrict__ X, const float* __restrict__ pad,
    const float* __restrict__ Wf, const float* __restrict__ Wb,
    const float* __restrict__ bf, const float* __restrict__ bb,
    float* __restrict__ gi)
{
  __shared__ __align__(16) unsigned short Ah[GBM * ASTR];
  __shared__ __align__(16) unsigned short Al[GBM * ASTR];
  __shared__ __align__(16) unsigned short Bh[GBN * ASTR];
  __shared__ __align__(16) unsigned short Bl[GBN * ASTR];

  const int bnb = blockIdx.x;          // n-block 0..23  (x fast => A-tile L2 reuse)
  const int bmb = blockIdx.y;          // m-block 0..63
  const int tid = threadIdx.x;
  const int m0 = bmb * GBM, n0 = bnb * GBN;
  const bool isF = (n0 < H3);
  const float* Wmat = isF ? Wf : Wb;
  const float* bias = isF ? bf : bb;
  const int nb0 = isF ? n0 : (n0 - H3);

  // staging role: each thread owns row r (A and B), k-half of 32
  const int r = tid >> 1, half = tid & 1;
  const int m = m0 + r;
  const int ab = m >> 8, tpos = m & 255;
  const float* wrowp = Wmat + (size_t)(nb0 + r) * K3;

  // mfma role
  const int wave = tid >> 6, lane = tid & 63;
  const int wr = wave >> 1, wc = wave & 1;
  const int lrow = lane & 15, lk = (lane >> 4) * 8;

  f32x4 acc[4][4];
#pragma unroll
  for (int i = 0; i < 4; i++)
#pragma unroll
    for (int j = 0; j < 4; j++) acc[i][j] = (f32x4){0.f, 0.f, 0.f, 0.f};

  for (int k0 = 0; k0 < K3; k0 += GBK) {
    // ---- stage A (virtual trigram lmr) and B (Wih rows), split hi/lo bf16 ----
#pragma unroll
    for (int j2 = 0; j2 < 4; j2++) {
      const int kg = k0 + half * 32 + j2 * 8;
      // segment never crossed within an aligned 8-run (768 % 8 == 0; 768 % 64 == 0)
      const int seg = (kg >= DIN) + (kg >= 2 * DIN);
      const int off = kg - seg * DIN;
      const int p = tpos + seg;
      const float* srcA = (p == 0 || p == Tn + 1)
                            ? (pad + off)
                            : (X + (size_t)(ab * Tn + (p - 1)) * DIN + off);
      float4 a0 = *reinterpret_cast<const float4*>(srcA);
      float4 a1 = *reinterpret_cast<const float4*>(srcA + 4);
      const float* srcB = wrowp + kg;
      float4 b0 = *reinterpret_cast<const float4*>(srcB);
      float4 b1 = *reinterpret_cast<const float4*>(srcB + 4);

      float av[8] = {a0.x, a0.y, a0.z, a0.w, a1.x, a1.y, a1.z, a1.w};
      float bv[8] = {b0.x, b0.y, b0.z, b0.w, b1.x, b1.y, b1.z, b1.w};
      short8v ah8, al8, bh8, bl8;
#pragma unroll
      for (int q = 0; q < 8; q++) {
        unsigned short h = f2bf(av[q]);
        ah8[q] = (short)h;
        al8[q] = (short)f2bf(av[q] - bf2f(h));
        unsigned short g = f2bf(bv[q]);
        bh8[q] = (short)g;
        bl8[q] = (short)f2bf(bv[q] - bf2f(g));
      }
      const int si = r * ASTR + half * 32 + j2 * 8;
      *reinterpret_cast<short8v*>(&Ah[si]) = ah8;
      *reinterpret_cast<short8v*>(&Al[si]) = al8;
      *reinterpret_cast<short8v*>(&Bh[si]) = bh8;
      *reinterpret_cast<short8v*>(&Bl[si]) = bl8;
    }
    __syncthreads();

    // ---- 2 k-subtiles: fragments + 48 MFMA each (3 split terms x 4x4 tiles) ----
#pragma unroll
    for (int ksub = 0; ksub < 2; ksub++) {
      short8v fah[4], fal[4], fbh[4], fbl[4];
#pragma unroll
      for (int i = 0; i < 4; i++) {
        const int ai = (wr * 64 + i * 16 + lrow) * ASTR + ksub * 32 + lk;
        const int bi = (wc * 64 + i * 16 + lrow) * ASTR + ksub * 32 + lk;
        fah[i] = *reinterpret_cast<const short8v*>(&Ah[ai]);
        fal[i] = *reinterpret_cast<const short8v*>(&Al[ai]);
        fbh[i] = *reinterpret_cast<const short8v*>(&Bh[bi]);
        fbl[i] = *reinterpret_cast<const short8v*>(&Bl[bi]);
      }
#pragma unroll
      for (int mi = 0; mi < 4; mi++)
#pragma unroll
        for (int ni = 0; ni < 4; ni++) {
          acc[mi][ni] = __builtin_amdgcn_mfma_f32_16x16x32_bf16(fah[mi], fbh[ni], acc[mi][ni], 0, 0, 0);
          acc[mi][ni] = __builtin_amdgcn_mfma_f32_16x16x32_bf16(fah[mi], fbl[ni], acc[mi][ni], 0, 0, 0);
          acc[mi][ni] = __builtin_amdgcn_mfma_f32_16x16x32_bf16(fal[mi], fbh[ni], acc[mi][ni], 0, 0, 0);
        }
    }
    __syncthreads();
  }

  // ---- epilogue: + bih, store fp32 (C map: col=lane&15, row=(lane>>4)*4+reg) ----
#pragma unroll
  for (int ni = 0; ni < 4; ni++) {
    const int nl = wc * 64 + ni * 16 + (lane & 15);
    const float bvv = bias[nb0 + nl];
#pragma unroll
    for (int mi = 0; mi < 4; mi++) {
      const int mg = m0 + wr * 64 + mi * 16 + (lane >> 4) * 4;
#pragma unroll
      for (int reg = 0; reg < 4; reg++)
        gi[(size_t)(mg + reg) * NCOL + n0 + nl] = acc[mi][ni][reg] + bvv;
    }
  }
}

// ---------------- prep: Wp[d][slice(32)][u(16)][k(512)] float4 {r,z,n,0} + zero sync ----------------
__global__ __launch_bounds__(256) void prep_kernel(
    const float* __restrict__ Whh_f, const float* __restrict__ Whh_b,
    float4* __restrict__ Wp, unsigned* __restrict__ sync)
{
  int f = blockIdx.x * 256 + threadIdx.x;    // 0 .. 524287
  if (f < 8) sync[f * 32] = 0u;
  if (f >= 2 * 32 * 16 * 512) return;
  int k   = f & 511;
  int u   = (f >> 9) & 15;
  int slc = (f >> 13) & 31;
  int d   = f >> 18;
  const float* Wsrc = d ? Whh_b : Whh_f;
  int ug = slc * 16 + u;
  float4 v;
  v.x = Wsrc[(size_t)(0 * DHn + ug) * DHn + k];
  v.y = Wsrc[(size_t)(1 * DHn + ug) * DHn + k];
  v.z = Wsrc[(size_t)(2 * DHn + ug) * DHn + k];
  v.w = 0.f;
  Wp[f] = v;
}

// ---------------- etab[p][c] = emb[p] . Wc[c][1024:1049] ----------------
__global__ __launch_bounds__(128) void etab_kernel(
    const float* __restrict__ label_emb, const float* __restrict__ Wc,
    float* __restrict__ etab)
{
  int t = threadIdx.x;
  if (t >= 90) return;
  int p = t / Cn, c = t % Cn;
  float a = 0.f;
#pragma unroll
  for (int j = 0; j < DEn; j++)
    a = fmaf(label_emb[p * DEn + j], Wc[(size_t)c * 1049 + 1024 + j], a);
  etab[t] = a;
}

// ---------------- GRU recurrence: weights-stationary, MALL-routed exchange ----------------
// 512 threads: (ut 0..15, kq 0..15, bh 0..1); bit-identical math to the 256-thread version
// (same per-lane 32-FMA chains; same add-tree bit order 8,1,2,4).
#define HSTRIDE 12

__global__ __launch_bounds__(512) void gru_rec5_kernel(
    const float* __restrict__ gi,     // [8192][3072]
    const float4* __restrict__ Wp,    // [2][32][16][512] float4
    const float* __restrict__ bhh_f, const float* __restrict__ bhh_b,
    unsigned* __restrict__ sync,
    float* __restrict__ hex,
    float* __restrict__ out)          // [B][T][1024]
{
  __shared__ __align__(16) float4 Wl[16 * 512];       // 131,072 B
  __shared__ __align__(16) float hl[512 * HSTRIDE];   //  24,576 B

  const int bid = blockIdx.x;
  const int xcd = bid & 7;
  const int d = xcd >> 2, g = xcd & 3;
  const int sl = bid >> 3;
  const int tid = threadIdx.x;       // 0..511
  const int ut = tid >> 5;           // 0..15 (two per wave, 32-lane halves)
  const int kq2 = tid & 31;
  const int kq = kq2 & 15, bh = kq2 >> 4;
  const int grp = d * 4 + g;

  {
    const float4* src = Wp + (size_t)(d * 32 + sl) * 8192;
    for (int i = tid; i < 8192; i += 512) Wl[i] = src[i];
  }
  for (int i = tid; i < 512 * HSTRIDE; i += 512) hl[i] = 0.f;

  const float* bhh = d ? bhh_b : bhh_f;
  const int ug = sl * 16 + ut;
  const float br = bhh[ug], bz = bhh[DHn + ug], bn2 = bhh[2 * DHn + ug];
  // final owner batch for lanes kq<4: bits from scatter masks 1,2 then bh half
  const int blocal = ((kq & 1) << 1) | ((kq >> 1) & 1);
  const int b_l = bh * 4 + blocal;

  unsigned* cnt = sync + grp * 32;

  __syncthreads();

  for (int s = 0; s < Tn; s++) {
    const int t = d ? (Tn - 1 - s) : s;

    // gi prefetch (independent of exchange; hides MALL/HBM latency under poll)
    float ir = 0.f, iz = 0.f, inn = 0.f;
    if (kq < 4) {
      const int bg = g * 8 + b_l;
      const float* gp = gi + (size_t)(bg * Tn + t) * NCOL + d * H3 + ug;
      ir = gp[0]; iz = gp[DHn]; inn = gp[2 * DHn];
    }

    if (s > 0) {
      if (tid == 0) {
        const unsigned tgt = 32u * (unsigned)s;
        while (__hip_atomic_load(cnt, __ATOMIC_RELAXED, __HIP_MEMORY_SCOPE_SYSTEM) < tgt)
          __builtin_amdgcn_s_sleep(1);
      }
      __syncthreads();
      asm volatile("" ::: "memory");
      // readback h(s-1): 2048 u64 system loads, 4 per thread
      const uint64_t* src = reinterpret_cast<const uint64_t*>(
          hex + (size_t)(((s - 1) & 1) * 8 + grp) * (512 * 8));
#pragma unroll
      for (int j = 0; j < 4; j++) {
        int idx = tid + 512 * j;
        uint64_t v = __hip_atomic_load(src + idx,
                                       __ATOMIC_RELAXED, __HIP_MEMORY_SCOPE_SYSTEM);
        int fd = 2 * idx;
        int u = fd >> 3, b = fd & 7;
        *reinterpret_cast<uint64_t*>(&hl[u * HSTRIDE + b]) = v;
      }
      __syncthreads();
    }

    float acc[3][4];
#pragma unroll
    for (int gg = 0; gg < 3; gg++)
#pragma unroll
      for (int bb = 0; bb < 4; bb++) acc[gg][bb] = 0.f;

#pragma unroll 4
    for (int i = 0; i < 32; i++) {
      int k = i * 16 + kq;
      float4 wv = Wl[ut * 512 + k];
      float4 ha = *reinterpret_cast<const float4*>(&hl[k * HSTRIDE + bh * 4]);
      acc[0][0] = fmaf(wv.x, ha.x, acc[0][0]); acc[0][1] = fmaf(wv.x, ha.y, acc[0][1]);
      acc[0][2] = fmaf(wv.x, ha.z, acc[0][2]); acc[0][3] = fmaf(wv.x, ha.w, acc[0][3]);
      acc[1][0] = fmaf(wv.y, ha.x, acc[1][0]); acc[1][1] = fmaf(wv.y, ha.y, acc[1][1]);
      acc[1][2] = fmaf(wv.y, ha.z, acc[1][2]); acc[1][3] = fmaf(wv.y, ha.w, acc[1][3]);
      acc[2][0] = fmaf(wv.z, ha.x, acc[2][0]); acc[2][1] = fmaf(wv.z, ha.y, acc[2][1]);
      acc[2][2] = fmaf(wv.z, ha.z, acc[2][2]); acc[2][3] = fmaf(wv.z, ha.w, acc[2][3]);
    }

    // mask-8 full add (same first tree level as before)
#pragma unroll
    for (int gg = 0; gg < 3; gg++)
#pragma unroll
      for (int bb = 0; bb < 4; bb++)
        acc[gg][bb] += __shfl_xor(acc[gg][bb], 8);

    // mask-1 scatter (4 batches -> 2)
    float a2[3][2];
#pragma unroll
    for (int gg = 0; gg < 3; gg++)
#pragma unroll
      for (int j = 0; j < 2; j++) {
        float keep = (kq & 1) ? acc[gg][2 + j] : acc[gg][j];
        float send = (kq & 1) ? acc[gg][j] : acc[gg][2 + j];
        a2[gg][j] = keep + __shfl_xor(send, 1);
      }
    // mask-2 scatter (2 -> 1)
    float a1[3];
#pragma unroll
    for (int gg = 0; gg < 3; gg++) {
      float keep = (kq & 2) ? a2[gg][1] : a2[gg][0];
      float send = (kq & 2) ? a2[gg][0] : a2[gg][1];
      a1[gg] = keep + __shfl_xor(send, 2);
    }
    // mask-4 full add (completes the 16-lane sum; same bit order 8,1,2,4)
#pragma unroll
    for (int gg = 0; gg < 3; gg++)
      a1[gg] += __shfl_xor(a1[gg], 4);

    float hnew = 0.f;
    if (kq < 4) {
      const float r = 1.f / (1.f + expf(-(ir + a1[0] + br)));
      const float z = 1.f / (1.f + expf(-(iz + a1[1] + bz)));
      const float n = tanhf(inn + r * (a1[2] + bn2));
      const float hold = hl[ug * HSTRIDE + b_l];
      hnew = (1.f - z) * n + z * hold;
      // system-scope (MALL) store: visible to peer XCDs without cache maintenance
      __hip_atomic_store(&hex[((size_t)(s & 1) * 8 + grp) * (512 * 8) + ug * 8 + b_l],
                         hnew, __ATOMIC_RELAXED, __HIP_MEMORY_SCOPE_SYSTEM);
    }
    // drain hex stores (vmcnt(0) per wave) before release
    __syncthreads();
    if (s < Tn - 1 && tid == 0)
      __hip_atomic_fetch_add(cnt, 1u, __ATOMIC_RELAXED, __HIP_MEMORY_SCOPE_SYSTEM);
    // out store off the release path (drained by next step's barrier)
    if (kq < 4)
      out[(size_t)((g * 8 + b_l) * Tn + t) * 1024 + d * DHn + ug] = hnew;
  }
}

// ---------------- lh[b*T+t][c] = h . Wc[c][:1024] + bc[c]  (feedback-free part) ----------------
__global__ __launch_bounds__(256) void lh_kernel(
    const float* __restrict__ out_h, const float* __restrict__ Wc,
    const float* __restrict__ bc, float* __restrict__ lh)
{
  const int tid = threadIdx.x;
  const int wave = tid >> 6, lane = tid & 63;
#pragma unroll 1
  for (int it = 0; it < 16; it++) {
    const int row = blockIdx.x * 64 + wave * 16 + it;
    const float* hp = out_h + (size_t)row * 1024 + lane * 4;
    float4 hv[4];
#pragma unroll
    for (int j = 0; j < 4; j++) hv[j] = *reinterpret_cast<const float4*>(hp + 256 * j);
    float acc[Cn];
#pragma unroll
    for (int c = 0; c < Cn; c++) {
      const float* wp = Wc + (size_t)c * 1049 + lane * 4;
      float a = 0.f;
#pragma unroll
      for (int j = 0; j < 4; j++) {
        float4 wv = *reinterpret_cast<const float4*>(wp + 256 * j);
        a = fmaf(hv[j].x, wv.x, a); a = fmaf(hv[j].y, wv.y, a);
        a = fmaf(hv[j].z, wv.z, a); a = fmaf(hv[j].w, wv.w, a);
      }
      acc[c] = a;
    }
#pragma unroll
    for (int off = 32; off; off >>= 1)
#pragma unroll
      for (int c = 0; c < Cn; c++) acc[c] += __shfl_xor(acc[c], off);
    if (lane < Cn) lh[(size_t)row * 12 + lane] = acc[lane] + bc[lane];
  }
}

// ---------------- chain: per-batch argmax feedback, 9 adds/step ----------------
__global__ __launch_bounds__(64) void chain_kernel(
    const float* __restrict__ lh,   // [8192][12]
    const float* __restrict__ etab, // [10][9]
    float* __restrict__ outc)       // [8192][9]
{
  __shared__ float et[90];
  const int tid = threadIdx.x;
  if (tid < 90) et[tid] = etab[tid];
  __syncthreads();
  if (tid >= Bn) return;
  const int b = tid;
  const float* base = lh + (size_t)b * Tn * 12;
  float4 A0 = *reinterpret_cast<const float4*>(base);
  float4 A1 = *reinterpret_cast<const float4*>(base + 4);
  float c8 = base[8];
  int prev = Cn;
  for (int t = 0; t < Tn; t++) {
    float4 N0 = {0,0,0,0}, N1 = {0,0,0,0}; float nc8 = 0.f;
    if (t < Tn - 1) {
      const float* nb = base + (size_t)(t + 1) * 12;
      N0 = *reinterpret_cast<const float4*>(nb);
      N1 = *reinterpret_cast<const float4*>(nb + 4);
      nc8 = nb[8];
    }
    float lg[Cn] = {A0.x, A0.y, A0.z, A0.w, A1.x, A1.y, A1.z, A1.w, c8};
    const float* ep = &et[prev * Cn];
#pragma unroll
    for (int c = 0; c < Cn; c++) lg[c] += ep[c];
    float mx = lg[0]; int idx = 0;
#pragma unroll
    for (int c = 1; c < Cn; c++) if (lg[c] > mx) { mx = lg[c]; idx = c; }
    float e[Cn]; float sum = 0.f;
#pragma unroll
    for (int c = 0; c < Cn; c++) { e[c] = expf(lg[c] - mx); sum += e[c]; }
    const float inv = 1.f / sum;
    float* op = outc + ((size_t)b * Tn + t) * Cn;
#pragma unroll
    for (int c = 0; c < Cn; c++) op[c] = e[c] * inv;
    prev = idx;
    A0 = N0; A1 = N1; c8 = nc8;
  }
}

extern "C" void kernel_launch(void* const* d_in, const int* in_sizes, int n_in,
                              void* d_out, int out_size, void* d_ws, size_t ws_size,
                              hipStream_t stream) {
  const float* X      = (const float*)d_in[0];
  const float* pad    = (const float*)d_in[1];
  const float* lemb   = (const float*)d_in[2];
  const float* Wih_f  = (const float*)d_in[3];
  const float* Whh_f  = (const float*)d_in[4];
  const float* bih_f  = (const float*)d_in[5];
  const float* bhh_f  = (const float*)d_in[6];
  const float* Wih_b  = (const float*)d_in[7];
  const float* Whh_b  = (const float*)d_in[8];
  const float* bih_b  = (const float*)d_in[9];
  const float* bhh_b  = (const float*)d_in[10];
  const float* Wc     = (const float*)d_in[11];
  const float* bc     = (const float*)d_in[12];
  float* out = (float*)d_out;

  char* ws = (char*)d_ws;
  float*    gi   = (float*)ws;                                  // 100,663,296 B
  float4*   Wp   = (float4*)(ws + (size_t)MROW * NCOL * 4);     // 8,388,608 B
  unsigned* sync = (unsigned*)(ws + (size_t)MROW * NCOL * 4 + 8388608);      // 1,024 B
  float*    hex  = (float*)(ws + (size_t)MROW * NCOL * 4 + 8388608 + 1024);  // 262,144 B
  // lh + etab overlap the (dead-after-gru) gi region; etab_kernel runs AFTER gru.
  float*    lh   = (float*)ws;                                  // 393,216 B
  float*    etab = (float*)(ws + 524288);                       // 360 B

  prep_kernel<<<dim3(2048), dim3(256), 0, stream>>>(Whh_f, Whh_b, Wp, sync);
  gi_gemm_mfma_kernel<<<dim3(NCOL / GBN, MROW / GBM), dim3(256), 0, stream>>>(
      X, pad, Wih_f, Wih_b, bih_f, bih_b, gi);
  gru_rec5_kernel<<<dim3(256), dim3(512), 0, stream>>>(gi, Wp, bhh_f, bhh_b, sync, hex, out);
  etab_kernel<<<dim3(1), dim3(128), 0, stream>>>(lemb, Wc, etab);   // after gru: gi region dead
  lh_kernel<<<dim3(128), dim3(256), 0, stream>>>(out, Wc, bc, lh);
  chain_kernel<<<dim3(1), dim3(64), 0, stream>>>(lh, etab, out + (size_t)MROW * 1024);
}